// Round 5
// baseline (1620.499 us; speedup 1.0000x reference)
//
#include <hip/hip_runtime.h>

using uint = unsigned int;
using u16  = unsigned short;
using ll   = long long;

constexpr int cL = 4, cH = 12, cDH = 64, cD = 768, cM = 3072, cV = 32000, cS = 1024, cB = 2;
constexpr int cT  = cB * cS;   // 2048 tokens
constexpr int cBH = cB * cH;   // 24
constexpr int cQKV = 3 * cD;   // 2304

using bf16x8 = __bf16 __attribute__((ext_vector_type(8)));
using f32x4  = float  __attribute__((ext_vector_type(4)));

__device__ __forceinline__ float b2f(u16 u) {
    union { uint i; float f; } v; v.i = ((uint)u) << 16; return v.f;
}
__device__ __forceinline__ u16 f2b(float f) {
    union { float f; uint i; } v; v.f = f;
    uint u = v.i;
    return (u16)((u + 0x7fffu + ((u >> 16) & 1u)) >> 16);   // RNE
}
// read input element `idx` as float, per mode (1 = bf16, 0 = f32)
__device__ __forceinline__ float inp(const void* p, ll idx, int md) {
    return md ? b2f(((const u16*)p)[idx]) : ((const float*)p)[idx];
}
__device__ __forceinline__ float wave_sum(float v) {
    #pragma unroll
    for (int m = 32; m; m >>= 1) v += __shfl_xor(v, m);
    return v;
}
__device__ __forceinline__ float wave_max(float v) {
    #pragma unroll
    for (int m = 32; m; m >>= 1) v = fmaxf(v, __shfl_xor(v, m));
    return v;
}
__device__ __forceinline__ void gload16(const u16* g, u16* l) {
    __builtin_amdgcn_global_load_lds(
        (const __attribute__((address_space(1))) uint*)g,
        (__attribute__((address_space(3))) uint*)l,
        16, 0, 0);
}

// ---------------- dtype detector ------------------------------------------------------
__global__ void detect_k(const uint* __restrict__ e, int* __restrict__ flag)
{
    const int l = threadIdx.x;
    int hits = 0;
    #pragma unroll
    for (int i = 0; i < 4; ++i) {
        uint w  = e[l * 4 + i];
        uint ex = (w >> 7) & 0xffu;
        hits += (ex >= 100u && ex <= 126u) ? 1 : 0;
    }
    float s = wave_sum((float)hits);
    if (l == 0) *flag = (s >= 128.f) ? 1 : 0;   // 1 = bf16 inputs, 0 = f32 inputs
}

// ---------------- pack QKV biases -> f32 [L][2304] ------------------------------------
__global__ __launch_bounds__(256)
void packbias_k(const void* __restrict__ Qb, const void* __restrict__ Kb,
                const void* __restrict__ Vb, float* __restrict__ out,
                const int* __restrict__ modeflag)
{
    const int md = *modeflag;
    const int i = blockIdx.x * 256 + threadIdx.x;   // i < L*2304
    const int l = i / cQKV, c = i % cQKV;
    float v;
    if (c < cD)           v = inp(Qb, (ll)l * cD + c, md);
    else if (c < 2 * cD)  v = inp(Kb, (ll)l * cD + c - cD, md);
    else                  v = inp(Vb, (ll)l * cD + c - 2 * cD, md);
    out[i] = v;
}

// =============== gemm256: 8-wave 256x256 tile, BK=32, tri-buffered pipeline ===========
// C = A[M,K] * Bt[N,K]^T + bias; OUTK: 0=f32, 1=bf16, 2=dynamic; BIASK: 0 none/1 inp/2 f32
// T2: LDS 16B-group swizzle g ^= (row>>1)&3, applied on global source AND ds_read.
// T3/T4: 2 phases per K-tile, prefetch distance 2, counted vmcnt(4). T5: setprio.
template<int OUTK, bool GELU, int BIASK>
__global__ __launch_bounds__(512, 1)
void gemm256(const u16* __restrict__ A, int lda,
             const u16* __restrict__ Bt, int ldb,
             void* __restrict__ Cv, int ldc, int K,
             const void* __restrict__ bias, ll bias_off,
             const int* __restrict__ modeflag)
{
    __shared__ __align__(16) u16 lds[3 * 16384];   // 3 bufs x (A 8192 + B 8192) u16

    const int md = *modeflag;
    const int rowTile = blockIdx.x * 256;
    const int colTile = blockIdx.y * 256;
    const int tid  = threadIdx.x;
    const int lane = tid & 63, wid = tid >> 6;
    const int wr = wid >> 2, wc = wid & 3;          // 2 x 4 waves, per-wave 128x64
    const int rs = tid >> 2, gs = tid & 3;          // staging row/16B-group
    const int nt = K >> 5;                          // BK = 32

    auto stageA = [&](int t, int h) {               // half h: rows [h*128, h*128+128)
        const int r = h * 128 + rs;
        const u16* src = A + (size_t)(rowTile + r) * lda + t * 32 + ((gs ^ ((r >> 1) & 3)) << 3);
        gload16(src, &lds[(t % 3) * 16384 + h * 4096 + wid * 512]);
    };
    auto stageB = [&](int t, int h) {
        const int r = h * 128 + rs;
        const u16* src = Bt + (size_t)(colTile + r) * ldb + t * 32 + ((gs ^ ((r >> 1) & 3)) << 3);
        gload16(src, &lds[(t % 3) * 16384 + 8192 + h * 4096 + wid * 512]);
    };

    f32x4 acc[8][4];
    #pragma unroll
    for (int m = 0; m < 8; ++m)
        #pragma unroll
        for (int n = 0; n < 4; ++n) acc[m][n] = f32x4{0.f, 0.f, 0.f, 0.f};

    // prologue: stage tiles 0 and 1
    stageA(0, 0); stageB(0, 0); stageA(0, 1); stageB(0, 1);
    if (nt > 1) { stageA(1, 0); stageB(1, 0); stageA(1, 1); stageB(1, 1); }
    if (nt > 1) asm volatile("s_waitcnt vmcnt(4)" ::: "memory");
    else        asm volatile("s_waitcnt vmcnt(0)" ::: "memory");
    __builtin_amdgcn_s_barrier();

    const int laneRA = lane & 15, cb16 = lane >> 4;
    for (int t = 0; t < nt; ++t) {
        const int bb = (t % 3) * 16384;
        bf16x8 bf[4], af[4];
        // ---- phase 0: B frags + A frags m=0..3; stage (t+2) half 0 ----
        #pragma unroll
        for (int n = 0; n < 4; ++n) {
            const int rb = wc * 64 + n * 16 + laneRA;
            bf[n] = *(const bf16x8*)&lds[bb + 8192 + rb * 32 + ((cb16 ^ ((rb >> 1) & 3)) << 3)];
        }
        #pragma unroll
        for (int m = 0; m < 4; ++m) {
            const int ra = wr * 128 + m * 16 + laneRA;
            af[m] = *(const bf16x8*)&lds[bb + ra * 32 + ((cb16 ^ ((ra >> 1) & 3)) << 3)];
        }
        if (t + 2 < nt) { stageA(t + 2, 0); stageB(t + 2, 0); }
        __builtin_amdgcn_s_barrier();
        asm volatile("s_waitcnt lgkmcnt(0)" ::: "memory");
        __builtin_amdgcn_sched_barrier(0);
        __builtin_amdgcn_s_setprio(1);
        #pragma unroll
        for (int m = 0; m < 4; ++m)
            #pragma unroll
            for (int n = 0; n < 4; ++n)
                acc[m][n] = __builtin_amdgcn_mfma_f32_16x16x32_bf16(af[m], bf[n], acc[m][n], 0, 0, 0);
        __builtin_amdgcn_s_setprio(0);
        __builtin_amdgcn_s_barrier();
        // ---- phase 1: A frags m=4..7; stage (t+2) half 1; counted vmcnt ----
        #pragma unroll
        for (int m = 0; m < 4; ++m) {
            const int ra = wr * 128 + (m + 4) * 16 + laneRA;
            af[m] = *(const bf16x8*)&lds[bb + ra * 32 + ((cb16 ^ ((ra >> 1) & 3)) << 3)];
        }
        if (t + 2 < nt) { stageA(t + 2, 1); stageB(t + 2, 1); }
        if (t + 2 < nt)      asm volatile("s_waitcnt vmcnt(4)" ::: "memory");
        else if (t + 1 < nt) asm volatile("s_waitcnt vmcnt(0)" ::: "memory");
        __builtin_amdgcn_s_barrier();
        asm volatile("s_waitcnt lgkmcnt(0)" ::: "memory");
        __builtin_amdgcn_sched_barrier(0);
        __builtin_amdgcn_s_setprio(1);
        #pragma unroll
        for (int m = 0; m < 4; ++m)
            #pragma unroll
            for (int n = 0; n < 4; ++n)
                acc[m + 4][n] = __builtin_amdgcn_mfma_f32_16x16x32_bf16(af[m], bf[n], acc[m + 4][n], 0, 0, 0);
        __builtin_amdgcn_s_setprio(0);
        __builtin_amdgcn_s_barrier();
    }

    // ---- epilogue ----
    #pragma unroll
    for (int n = 0; n < 4; ++n) {
        const int col = colTile + wc * 64 + n * 16 + laneRA;
        float bv = 0.f;
        if constexpr (BIASK == 1) bv = inp(bias, bias_off + col, md);
        if constexpr (BIASK == 2) bv = ((const float*)bias)[bias_off + col];
        #pragma unroll
        for (int m = 0; m < 8; ++m) {
            #pragma unroll
            for (int r = 0; r < 4; ++r) {
                const int row = rowTile + wr * 128 + m * 16 + ((lane >> 4) << 2) + r;
                float xv = acc[m][n][r] + bv;
                if constexpr (GELU) xv = 0.5f * xv * (1.f + erff(xv * 0.70710678118654752f));
                const size_t idx = (size_t)row * ldc + col;
                if constexpr (OUTK == 1)      ((u16*)Cv)[idx] = f2b(xv);
                else if constexpr (OUTK == 0) ((float*)Cv)[idx] = xv;
                else {
                    if (md) ((u16*)Cv)[idx] = f2b(xv);
                    else    ((float*)Cv)[idx] = xv;
                }
            }
        }
    }
}

// ---------------- GEMM (m97-style 128-tile, 4 waves) — small/odd shapes ---------------
template<int BM, int BN, int WGM, int WGN, int OUTK, bool GELU,
         bool COLMAJ, bool CSKIP, bool CK, int BIASK>
__global__ __launch_bounds__(256)
void gemm_bt(const u16* __restrict__ A, int lda, ll offAo, ll offAi,
             const u16* __restrict__ Bt, int ldb, ll offBo, ll offBi,
             void* __restrict__ Cv, int ldc, ll offCo, ll offCi,
             int HB, int K,
             const void* __restrict__ bias, ll bias_off, float scale,
             const float* __restrict__ r1, const float* __restrict__ r2,
             const int* __restrict__ modeflag)
{
    constexpr int MF = BM / WGM / 16;
    constexpr int NF = BN / WGN / 16;
    static_assert(BM % (WGM * 16) == 0 && BN % (WGN * 16) == 0, "tile/wave mismatch");
    static_assert(WGM * WGN == 4, "4 waves");
    __shared__ __align__(16) u16 sA[BM * 64];
    __shared__ __align__(16) u16 sB[BN * 64];

    const int rowTile = (COLMAJ ? blockIdx.x : blockIdx.y) * BM;
    const int colTile = (COLMAJ ? blockIdx.y : blockIdx.x) * BN;
    if constexpr (CSKIP) {
        if (colTile >= rowTile + BM) return;
    }

    const int md = *modeflag;
    const int z = blockIdx.z;
    const ll zo = z / HB, zi = z % HB;
    const u16* Ab = A + zo * offAo + zi * offAi;
    const u16* Bb = Bt + zo * offBo + zi * offBi;

    const int tid  = threadIdx.x;
    const int lane = tid & 63, wid = tid >> 6;
    const int wr = wid / WGN, wc = wid % WGN;
    const int lr = lane >> 3, lc8 = (lane & 7) << 3;

    f32x4 zero = {0.f, 0.f, 0.f, 0.f};
    f32x4 acc[MF][NF];
    #pragma unroll
    for (int m = 0; m < MF; ++m)
        #pragma unroll
        for (int n = 0; n < NF; ++n) acc[m][n] = zero;

    const int nkt = CK ? ((rowTile + BM) >> 6) : (K >> 6);
    for (int kt = 0; kt < nkt; ++kt) {
        const int k0 = kt << 6;
        #pragma unroll
        for (int i = 0; i < BM / 32; ++i) {
            int c = i * 4 + wid;
            gload16(Ab + (size_t)(rowTile + c * 8 + lr) * lda + k0 + lc8, &sA[c * 512]);
        }
        #pragma unroll
        for (int i = 0; i < BN / 32; ++i) {
            int c = i * 4 + wid;
            gload16(Bb + (size_t)(colTile + c * 8 + lr) * ldb + k0 + lc8, &sB[c * 512]);
        }
        asm volatile("s_waitcnt vmcnt(0)" ::: "memory");
        __syncthreads();
        #pragma unroll
        for (int kk = 0; kk < 2; ++kk) {
            const int ko = kk * 32 + (lane >> 4) * 8;
            bf16x8 af[MF], bfv[NF];
            #pragma unroll
            for (int m = 0; m < MF; ++m)
                af[m] = *(const bf16x8*)&sA[(wr * (BM / WGM) + m * 16 + (lane & 15)) * 64 + ko];
            #pragma unroll
            for (int n = 0; n < NF; ++n)
                bfv[n] = *(const bf16x8*)&sB[(wc * (BN / WGN) + n * 16 + (lane & 15)) * 64 + ko];
            #pragma unroll
            for (int m = 0; m < MF; ++m)
                #pragma unroll
                for (int n = 0; n < NF; ++n)
                    acc[m][n] = __builtin_amdgcn_mfma_f32_16x16x32_bf16(af[m], bfv[n], acc[m][n], 0, 0, 0);
        }
        __syncthreads();
    }

    const ll offC = zo * offCo + zi * offCi;
    #pragma unroll
    for (int m = 0; m < MF; ++m) {
        #pragma unroll
        for (int n = 0; n < NF; ++n) {
            const int col = colTile + wc * (BN / WGN) + n * 16 + (lane & 15);
            float bv = 0.f;
            if constexpr (BIASK == 1) bv = inp(bias, bias_off + col, md);
            if constexpr (BIASK == 2) bv = ((const float*)bias)[bias_off + col];
            #pragma unroll
            for (int r = 0; r < 4; ++r) {
                const int row = rowTile + wr * (BM / WGM) + m * 16 + ((lane >> 4) << 2) + r;
                float xv = acc[m][n][r] * scale + bv;
                if constexpr (GELU) xv = 0.5f * xv * (1.f + erff(xv * 0.70710678118654752f));
                const size_t idx = (size_t)row * ldc + col;
                if (r1) xv += r1[idx];
                if (r2) xv += r2[idx];
                if constexpr (OUTK == 1)      ((u16*)Cv)[offC + idx] = f2b(xv);
                else if constexpr (OUTK == 0) ((float*)Cv)[offC + idx] = xv;
                else {
                    if (md) ((u16*)Cv)[offC + idx] = f2b(xv);
                    else    ((float*)Cv)[offC + idx] = xv;
                }
            }
        }
    }
}

// ------- transpose input weight (bf16 OR f32) -> bf16 ---------------------------------
__global__ __launch_bounds__(256)
void transpose_k(const void* __restrict__ in, u16* __restrict__ out,
                 int R, int C, int ins, int outs,
                 ll base, ll iStride, ll oStride,
                 const int* __restrict__ modeflag)
{
    __shared__ u16 tile[32][33];
    const int md = *modeflag;
    const int z = blockIdx.z;
    const ll ioff = base + (ll)z * iStride;
    u16* op = out + (ll)z * oStride;
    const int tx = threadIdx.x & 31, ty = threadIdx.x >> 5;
    const int c0 = blockIdx.x * 32, r0 = blockIdx.y * 32;
    #pragma unroll
    for (int i = 0; i < 32; i += 8) {
        int r = r0 + ty + i, c = c0 + tx;
        if (r < R && c < C) tile[ty + i][tx] = f2b(inp(in, ioff + (ll)r * ins + c, md));
    }
    __syncthreads();
    #pragma unroll
    for (int i = 0; i < 32; i += 8) {
        int c = c0 + ty + i, r = r0 + tx;
        if (c < C && r < R) op[(size_t)c * outs + r] = tile[tx][ty + i];
    }
}

// ------- fused per-layer weight transposes: QKV + O + In + Out in ONE launch ----------
__global__ __launch_bounds__(256)
void transw_k(const void* __restrict__ Qw, const void* __restrict__ Kw,
              const void* __restrict__ Vw, const void* __restrict__ Ow,
              const void* __restrict__ Inw, const void* __restrict__ Outw,
              u16* __restrict__ WqkvT, u16* __restrict__ WoT,
              u16* __restrict__ WinT, u16* __restrict__ WoutT,
              int l, const int* __restrict__ modeflag)
{
    __shared__ u16 tile[32][33];
    const int md = *modeflag;
    const int b = blockIdx.x;
    const void* in; u16* out; int ins, outs, tx_, ty_; ll ibase;
    if (b < 1728) {                       // QKV: 3 segs x 12 heads x 48 tiles (2x24)
        const int seg = b / 576, rem = b % 576, hd = rem / 48, tt = rem % 48;
        in = seg == 0 ? Qw : (seg == 1 ? Kw : Vw);
        ibase = (ll)l * cH * cD * cDH + (ll)hd * cD * cDH;
        out = WqkvT + (ll)seg * cD * cD + (ll)hd * cDH * cD;
        ins = cDH; outs = cD; tx_ = tt % 2; ty_ = tt / 2;
    } else if (b < 2304) {                // O: 24 x 24
        const int tt = b - 1728;
        in = Ow; ibase = (ll)l * cD * cD; out = WoT;
        ins = cD; outs = cD; tx_ = tt % 24; ty_ = tt / 24;
    } else if (b < 4608) {                // In: 96 x 24
        const int tt = b - 2304;
        in = Inw; ibase = (ll)l * cD * cM; out = WinT;
        ins = cM; outs = cD; tx_ = tt % 96; ty_ = tt / 96;
    } else {                              // Out: 24 x 96
        const int tt = b - 4608;
        in = Outw; ibase = (ll)l * cM * cD; out = WoutT;
        ins = cD; outs = cM; tx_ = tt % 24; ty_ = tt / 24;
    }
    const int tx = threadIdx.x & 31, ty = threadIdx.x >> 5;
    const int c0 = tx_ * 32, r0 = ty_ * 32;
    #pragma unroll
    for (int i = 0; i < 32; i += 8)
        tile[ty + i][tx] = f2b(inp(in, ibase + (ll)(r0 + ty + i) * ins + c0 + tx, md));
    __syncthreads();
    #pragma unroll
    for (int i = 0; i < 32; i += 8)
        out[(size_t)(c0 + ty + i) * outs + (r0 + tx)] = tile[tx][ty + i];
}

// ---- bf16 transpose for internal V slice (qkv cols) ----------------------------------
__global__ __launch_bounds__(256)
void transpose_b_k(const u16* __restrict__ in, u16* __restrict__ out,
                   int R, int C, int ins, int outs,
                   ll iOo, ll iOi, ll oOo, ll oOi, int HB)
{
    __shared__ u16 tile[32][33];
    const int z = blockIdx.z;
    const u16* ip = in  + (ll)(z / HB) * iOo + (ll)(z % HB) * iOi;
    u16*       op = out + (ll)(z / HB) * oOo + (ll)(z % HB) * oOi;
    const int tx = threadIdx.x & 31, ty = threadIdx.x >> 5;
    const int c0 = blockIdx.x * 32, r0 = blockIdx.y * 32;
    #pragma unroll
    for (int i = 0; i < 32; i += 8) {
        int r = r0 + ty + i, c = c0 + tx;
        if (r < R && c < C) tile[ty + i][tx] = ip[(size_t)r * ins + c];
    }
    __syncthreads();
    #pragma unroll
    for (int i = 0; i < 32; i += 8) {
        int c = c0 + ty + i, r = r0 + tx;
        if (c < C && r < R) op[(size_t)c * outs + r] = tile[tx][ty + i];
    }
}

// ---------------- embedding: res = E[x] + P (f32 out) ---------------------------------
__global__ __launch_bounds__(192)
void embed_k(const int* __restrict__ x, const void* __restrict__ E,
             const void* __restrict__ P, float* __restrict__ res,
             const int* __restrict__ modeflag)
{
    const int md = *modeflag;
    const int tok = blockIdx.x, t = threadIdx.x;
    const int s = tok & (cS - 1);
    const ll  eb = (ll)x[tok] * cD, pb = (ll)s * cD;
    float4 o;
    o.x = inp(E, eb + t * 4 + 0, md) + inp(P, pb + t * 4 + 0, md);
    o.y = inp(E, eb + t * 4 + 1, md) + inp(P, pb + t * 4 + 1, md);
    o.z = inp(E, eb + t * 4 + 2, md) + inp(P, pb + t * 4 + 2, md);
    o.w = inp(E, eb + t * 4 + 3, md) + inp(P, pb + t * 4 + 3, md);
    ((float4*)(res + (size_t)tok * cD))[t] = o;
}

// ---------------- layernorm (unbiased std, ddof=1), f32 in, bf16 out ------------------
__global__ __launch_bounds__(192)
void ln_k(const float* __restrict__ in, const void* __restrict__ w,
          const void* __restrict__ b, ll wb_off, u16* __restrict__ out,
          const int* __restrict__ modeflag)
{
    __shared__ float sm[8];
    const int md = *modeflag;
    const int row = blockIdx.x, t = threadIdx.x;
    const float4 x = ((const float4*)(in + (size_t)row * cD))[t];
    float s = wave_sum(x.x + x.y + x.z + x.w);
    const int lane = t & 63, wv = t >> 6;
    if (!lane) sm[wv] = s;
    __syncthreads();
    const float mu = (sm[0] + sm[1] + sm[2]) * (1.f / (float)cD);
    const float dx = x.x - mu, dy = x.y - mu, dz = x.z - mu, dw = x.w - mu;
    float ss = wave_sum(dx * dx + dy * dy + dz * dz + dw * dw);
    if (!lane) sm[4 + wv] = ss;
    __syncthreads();
    const float var = (sm[4] + sm[5] + sm[6]) * (1.f / (float)(cD - 1));
    const float rs  = 1.f / sqrtf(var);
    const ll o4 = wb_off + (ll)t * 4;
    ushort4 o;
    o.x = f2b(inp(w, o4 + 0, md) * (dx * rs) + inp(b, o4 + 0, md));
    o.y = f2b(inp(w, o4 + 1, md) * (dy * rs) + inp(b, o4 + 1, md));
    o.z = f2b(inp(w, o4 + 2, md) * (dz * rs) + inp(b, o4 + 2, md));
    o.w = f2b(inp(w, o4 + 3, md) * (dw * rs) + inp(b, o4 + 3, md));
    ((ushort4*)(out + (size_t)row * cD))[t] = o;
}

// ---------------- causal softmax, in-place on bf16 [rows=BH*S][S] ----------------------
__global__ __launch_bounds__(256)
void softmax_k(u16* __restrict__ p)
{
    __shared__ float sm[8];
    const int row = blockIdx.x;
    const int q = row & (cS - 1);
    u16* pr = p + (size_t)row * cS;
    const int t = threadIdx.x;
    const int j0 = t * 4;
    ushort4 v = {0, 0, 0, 0};
    if (j0 <= q) v = ((const ushort4*)pr)[t];
    float x0 = (j0 + 0 <= q) ? b2f(v.x) : -100000.f;
    float x1 = (j0 + 1 <= q) ? b2f(v.y) : -100000.f;
    float x2 = (j0 + 2 <= q) ? b2f(v.z) : -100000.f;
    float x3 = (j0 + 3 <= q) ? b2f(v.w) : -100000.f;
    float mx = wave_max(fmaxf(fmaxf(x0, x1), fmaxf(x2, x3)));
    const int lane = t & 63, wv = t >> 6;
    if (!lane) sm[wv] = mx;
    __syncthreads();
    const float MX = fmaxf(fmaxf(sm[0], sm[1]), fmaxf(sm[2], sm[3]));
    const float e0 = expf(x0 - MX), e1 = expf(x1 - MX), e2 = expf(x2 - MX), e3 = expf(x3 - MX);
    float ssum = wave_sum(e0 + e1 + e2 + e3);
    if (!lane) sm[4 + wv] = ssum;
    __syncthreads();
    const float inv = 1.f / (sm[4] + sm[5] + sm[6] + sm[7]);
    ushort4 o;
    o.x = f2b(e0 * inv); o.y = f2b(e1 * inv); o.z = f2b(e2 * inv); o.w = f2b(e3 * inv);
    ((ushort4*)pr)[t] = o;
}

// =====================================================================================
extern "C" void kernel_launch(void* const* d_in, const int* in_sizes, int n_in,
                              void* d_out, int out_size, void* d_ws, size_t ws_size,
                              hipStream_t stream)
{
    (void)in_sizes; (void)n_in; (void)out_size;
    const int*  x     = (const int*)d_in[0];
    const void* E_w   = d_in[1];
    const void* P_w   = d_in[2];
    const void* ln1_w = d_in[3];
    const void* ln1_b = d_in[4];
    const void* Q_w   = d_in[5];
    const void* Q_b   = d_in[6];
    const void* K_w   = d_in[7];
    const void* K_b   = d_in[8];
    const void* V_w   = d_in[9];
    const void* V_b   = d_in[10];
    const void* O_w   = d_in[11];
    const void* O_b   = d_in[12];
    const void* ln2_w = d_in[13];
    const void* ln2_b = d_in[14];
    const void* In_w  = d_in[15];
    const void* In_b  = d_in[16];
    const void* Out_w = d_in[17];
    const void* Out_b = d_in[18];
    const void* lnf_w = d_in[19];
    const void* lnf_b = d_in[20];
    const void* U_w   = d_in[21];
    const void* U_b   = d_in[22];

    // ---- workspace carve with aliasing (~99 MB) ----
    char* wp = (char*)d_ws;
    auto carve = [&](size_t bytes) { char* r = wp; wp += (bytes + 255) & ~(size_t)255; return r; };
    int*   modeflag = (int*)carve(256);
    float* biasQKV  = (float*)carve((size_t)cL * cQKV * 4);
    float* res   = (float*)carve((size_t)cT * cD * 4);
    float* resat = (float*)carve((size_t)cT * cD * 4);
    u16* h     = (u16*)carve((size_t)cT * cD * 2);
    u16* attnb = (u16*)carve((size_t)cT * cD * 2);
    u16* vt    = (u16*)carve((size_t)cT * cD * 2);
    u16* qkv   = (u16*)carve((size_t)cT * cM * 2);       // aliased by mlpb
    u16* mlpb  = qkv;
    u16* WqkvT = (u16*)carve((size_t)cQKV * cD * 2);
    u16* WoT   = (u16*)carve((size_t)cD * cD * 2);
    u16* WinT  = (u16*)carve((size_t)cD * cM * 2);
    u16* WoutT = (u16*)carve((size_t)cD * cM * 2);
    u16* pbuf  = (u16*)carve((size_t)cBH * cS * cS * 2);
    u16* WuT   = pbuf;                                   // alias (pbuf dead after layers)

    if (ws_size && (size_t)(wp - (char*)d_ws) > ws_size) return;  // tripwire

    detect_k<<<1, 64, 0, stream>>>((const uint*)E_w, modeflag);
    packbias_k<<<(cL * cQKV) / 256, 256, 0, stream>>>(Q_b, K_b, V_b, biasQKV, modeflag);
    embed_k<<<cT, 192, 0, stream>>>(x, E_w, P_w, res, modeflag);

    for (int l = 0; l < cL; ++l) {
        // fused weight transposes for this layer (1 launch)
        transw_k<<<6912, 256, 0, stream>>>(Q_w, K_w, V_w, O_w, In_w, Out_w,
                                           WqkvT, WoT, WinT, WoutT, l, modeflag);

        // LN1
        ln_k<<<cT, 192, 0, stream>>>(res, ln1_w, ln1_b, (ll)l * cD, h, modeflag);

        // fused QKV projection (gemm256): [2048,768] @ [2304,768]^T -> qkv
        gemm256<1, false, 2><<<dim3(cT / 256, cQKV / 256, 1), 512, 0, stream>>>(
            h, cD, WqkvT, cD, qkv, cQKV, cD, biasQKV, (ll)l * cQKV, modeflag);

        // V slice -> vt [B,H,DH,S]
        transpose_b_k<<<dim3(2, cS / 32, cBH), 256, 0, stream>>>(
            qkv + 2 * cD, vt, cS, cDH, cQKV, cS,
            (ll)cS * cQKV, cDH, (ll)cH * cDH * cS, (ll)cDH * cS, cH);

        // logits = Q K^T * 1/8, batched over (b,h), causal tile skip
        gemm_bt<128, 128, 2, 2, 1, false, false, true, false, 0>
            <<<dim3(8, 8, cBH), 256, 0, stream>>>(
            qkv, cQKV, (ll)cS * cQKV, cDH,
            qkv + cD, cQKV, (ll)cS * cQKV, cDH,
            pbuf, cS, (ll)cH * cS * cS, (ll)cS * cS,
            cH, cDH, nullptr, 0, 0.125f, nullptr, nullptr, modeflag);

        softmax_k<<<cBH * cS, 256, 0, stream>>>(pbuf);

        // attn = P V, batched, causal K-limit
        gemm_bt<128, 64, 4, 1, 1, false, false, false, true, 0>
            <<<dim3(1, 8, cBH), 256, 0, stream>>>(
            pbuf, cS, (ll)cH * cS * cS, (ll)cS * cS,
            vt, cS, (ll)cH * cDH * cS, (ll)cDH * cS,
            attnb, cD, (ll)cS * cD, cDH,
            cH, cS, nullptr, 0, 1.f, nullptr, nullptr, modeflag);

        // O projection + residual -> resat (f32)
        gemm_bt<128, 128, 2, 2, 0, false, true, false, false, 1>
            <<<dim3(cT / 128, cD / 128, 1), 256, 0, stream>>>(
            attnb, cD, 0, 0, WoT, cD, 0, 0, resat, cD, 0, 0, 1, cD,
            O_b, (ll)l * cD, 1.f, res, nullptr, modeflag);

        // LN2
        ln_k<<<cT, 192, 0, stream>>>(resat, ln2_w, ln2_b, (ll)l * cD, h, modeflag);

        // MLP in (gemm256): gelu(h @ Win + bIn)
        gemm256<1, true, 1><<<dim3(cT / 256, cM / 256, 1), 512, 0, stream>>>(
            h, cD, WinT, cD, mlpb, cM, cD, In_b, (ll)l * cM, modeflag);

        // MLP out + double residual: res = res + resat + (m @ Wout + bOut)
        gemm_bt<128, 128, 2, 2, 0, false, true, false, false, 1>
            <<<dim3(cT / 128, cD / 128, 1), 256, 0, stream>>>(
            mlpb, cM, 0, 0, WoutT, cM, 0, 0, res, cD, 0, 0, 1, cM,
            Out_b, (ll)l * cD, 1.f, res, resat, modeflag);
    }

    // unembed weight transpose (WuT aliases pbuf), final LN, unembed (gemm256)
    transpose_k<<<dim3(cV / 32, cD / 32, 1), 256, 0, stream>>>(
        U_w, WuT, cD, cV, cV, cD, 0, 0, 0, modeflag);
    ln_k<<<cT, 192, 0, stream>>>(res, lnf_w, lnf_b, 0, h, modeflag);
    gemm256<2, false, 1><<<dim3(cT / 256, cV / 256, 1), 512, 0, stream>>>(
        h, cD, WuT, cD, d_out, cV, cD, U_b, 0, modeflag);
}

// Round 6
// 1308.645 us; speedup vs baseline: 1.2383x; 1.2383x over previous
//
#include <hip/hip_runtime.h>

using uint = unsigned int;
using u16  = unsigned short;
using ll   = long long;

constexpr int cL = 4, cH = 12, cDH = 64, cD = 768, cM = 3072, cV = 32000, cS = 1024, cB = 2;
constexpr int cT  = cB * cS;   // 2048 tokens
constexpr int cBH = cB * cH;   // 24
constexpr int cQKV = 3 * cD;   // 2304

using bf16x8 = __bf16 __attribute__((ext_vector_type(8)));
using f32x4  = float  __attribute__((ext_vector_type(4)));

__device__ __forceinline__ float b2f(u16 u) {
    union { uint i; float f; } v; v.i = ((uint)u) << 16; return v.f;
}
__device__ __forceinline__ u16 f2b(float f) {
    union { float f; uint i; } v; v.f = f;
    uint u = v.i;
    return (u16)((u + 0x7fffu + ((u >> 16) & 1u)) >> 16);   // RNE
}
// read input element `idx` as float, per mode (1 = bf16, 0 = f32)
__device__ __forceinline__ float inp(const void* p, ll idx, int md) {
    return md ? b2f(((const u16*)p)[idx]) : ((const float*)p)[idx];
}
__device__ __forceinline__ float wave_sum(float v) {
    #pragma unroll
    for (int m = 32; m; m >>= 1) v += __shfl_xor(v, m);
    return v;
}
__device__ __forceinline__ float wave_max(float v) {
    #pragma unroll
    for (int m = 32; m; m >>= 1) v = fmaxf(v, __shfl_xor(v, m));
    return v;
}
__device__ __forceinline__ void gload16(const u16* g, u16* l) {
    __builtin_amdgcn_global_load_lds(
        (const __attribute__((address_space(1))) uint*)g,
        (__attribute__((address_space(3))) uint*)l,
        16, 0, 0);
}

// ---------------- dtype detector ------------------------------------------------------
__global__ void detect_k(const uint* __restrict__ e, int* __restrict__ flag)
{
    const int l = threadIdx.x;
    int hits = 0;
    #pragma unroll
    for (int i = 0; i < 4; ++i) {
        uint w  = e[l * 4 + i];
        uint ex = (w >> 7) & 0xffu;
        hits += (ex >= 100u && ex <= 126u) ? 1 : 0;
    }
    float s = wave_sum((float)hits);
    if (l == 0) *flag = (s >= 128.f) ? 1 : 0;   // 1 = bf16 inputs, 0 = f32 inputs
}

// ---------------- pack QKV biases -> f32 [L][2304] ------------------------------------
__global__ __launch_bounds__(256)
void packbias_k(const void* __restrict__ Qb, const void* __restrict__ Kb,
                const void* __restrict__ Vb, float* __restrict__ out,
                const int* __restrict__ modeflag)
{
    const int md = *modeflag;
    const int i = blockIdx.x * 256 + threadIdx.x;   // i < L*2304
    const int l = i / cQKV, c = i % cQKV;
    float v;
    if (c < cD)           v = inp(Qb, (ll)l * cD + c, md);
    else if (c < 2 * cD)  v = inp(Kb, (ll)l * cD + c - cD, md);
    else                  v = inp(Vb, (ll)l * cD + c - 2 * cD, md);
    out[i] = v;
}

// =============== gemm256: 8-wave 256x256 tile, BK=32, tri-buffered pipeline ===========
// C = A[M,K] * Bt[N,K]^T + bias; OUTK: 0=f32, 1=bf16, 2=dynamic; BIASK: 0 none/1 inp/2 f32
// T1: bijective XCD swizzle (m204). T2: LDS 16B-group swizzle both-sides. T3/T4: 2-phase
// K-pipeline, prefetch distance 2, counted vmcnt(4). T5: setprio around MFMA cluster.
template<int OUTK, bool GELU, int BIASK>
__global__ __launch_bounds__(512, 1)
void gemm256(const u16* __restrict__ A, int lda,
             const u16* __restrict__ Bt, int ldb,
             void* __restrict__ Cv, int ldc, int K,
             const void* __restrict__ bias, ll bias_off,
             const int* __restrict__ modeflag)
{
    __shared__ __align__(16) u16 lds[3 * 16384];   // 3 bufs x (A 8192 + B 8192) u16

    // T1: bijective XCD-aware remap of the linear block id (8 XCDs, round-robin dispatch)
    const int nwg = gridDim.x * gridDim.y;
    const int lin = blockIdx.y * gridDim.x + blockIdx.x;
    const int q8 = nwg >> 3, r8 = nwg & 7;
    const int xcd = lin & 7, idx = lin >> 3;
    const int n_  = (xcd < r8 ? xcd * (q8 + 1) : r8 * (q8 + 1) + (xcd - r8) * q8) + idx;
    const int rowTile = (n_ % gridDim.x) * 256;
    const int colTile = (n_ / gridDim.x) * 256;

    const int md = *modeflag;
    const int tid  = threadIdx.x;
    const int lane = tid & 63, wid = tid >> 6;
    const int wr = wid >> 2, wc = wid & 3;          // 2 x 4 waves, per-wave 128x64
    const int rs = tid >> 2, gs = tid & 3;          // staging row/16B-group
    const int nt = K >> 5;                          // BK = 32

    auto stageA = [&](int t, int h) {               // half h: rows [h*128, h*128+128)
        const int r = h * 128 + rs;
        const u16* src = A + (size_t)(rowTile + r) * lda + t * 32 + ((gs ^ ((r >> 1) & 3)) << 3);
        gload16(src, &lds[(t % 3) * 16384 + h * 4096 + wid * 512]);
    };
    auto stageB = [&](int t, int h) {
        const int r = h * 128 + rs;
        const u16* src = Bt + (size_t)(colTile + r) * ldb + t * 32 + ((gs ^ ((r >> 1) & 3)) << 3);
        gload16(src, &lds[(t % 3) * 16384 + 8192 + h * 4096 + wid * 512]);
    };

    f32x4 acc[8][4];
    #pragma unroll
    for (int m = 0; m < 8; ++m)
        #pragma unroll
        for (int n = 0; n < 4; ++n) acc[m][n] = f32x4{0.f, 0.f, 0.f, 0.f};

    // prologue: stage tiles 0 and 1
    stageA(0, 0); stageB(0, 0); stageA(0, 1); stageB(0, 1);
    if (nt > 1) { stageA(1, 0); stageB(1, 0); stageA(1, 1); stageB(1, 1); }
    if (nt > 1) asm volatile("s_waitcnt vmcnt(4)" ::: "memory");
    else        asm volatile("s_waitcnt vmcnt(0)" ::: "memory");
    __builtin_amdgcn_s_barrier();

    const int laneRA = lane & 15, cb16 = lane >> 4;
    for (int t = 0; t < nt; ++t) {
        const int bb = (t % 3) * 16384;
        bf16x8 bf[4], af[4];
        // ---- phase 0: B frags + A frags m=0..3; stage (t+2) half 0 ----
        #pragma unroll
        for (int n = 0; n < 4; ++n) {
            const int rb = wc * 64 + n * 16 + laneRA;
            bf[n] = *(const bf16x8*)&lds[bb + 8192 + rb * 32 + ((cb16 ^ ((rb >> 1) & 3)) << 3)];
        }
        #pragma unroll
        for (int m = 0; m < 4; ++m) {
            const int ra = wr * 128 + m * 16 + laneRA;
            af[m] = *(const bf16x8*)&lds[bb + ra * 32 + ((cb16 ^ ((ra >> 1) & 3)) << 3)];
        }
        if (t + 2 < nt) { stageA(t + 2, 0); stageB(t + 2, 0); }
        __builtin_amdgcn_s_barrier();
        asm volatile("s_waitcnt lgkmcnt(0)" ::: "memory");
        __builtin_amdgcn_sched_barrier(0);
        __builtin_amdgcn_s_setprio(1);
        #pragma unroll
        for (int m = 0; m < 4; ++m)
            #pragma unroll
            for (int n = 0; n < 4; ++n)
                acc[m][n] = __builtin_amdgcn_mfma_f32_16x16x32_bf16(af[m], bf[n], acc[m][n], 0, 0, 0);
        __builtin_amdgcn_s_setprio(0);
        __builtin_amdgcn_s_barrier();
        // ---- phase 1: A frags m=4..7; stage (t+2) half 1; counted vmcnt ----
        #pragma unroll
        for (int m = 0; m < 4; ++m) {
            const int ra = wr * 128 + (m + 4) * 16 + laneRA;
            af[m] = *(const bf16x8*)&lds[bb + ra * 32 + ((cb16 ^ ((ra >> 1) & 3)) << 3)];
        }
        if (t + 2 < nt) { stageA(t + 2, 1); stageB(t + 2, 1); }
        if (t + 2 < nt)      asm volatile("s_waitcnt vmcnt(4)" ::: "memory");
        else if (t + 1 < nt) asm volatile("s_waitcnt vmcnt(0)" ::: "memory");
        __builtin_amdgcn_s_barrier();
        asm volatile("s_waitcnt lgkmcnt(0)" ::: "memory");
        __builtin_amdgcn_sched_barrier(0);
        __builtin_amdgcn_s_setprio(1);
        #pragma unroll
        for (int m = 0; m < 4; ++m)
            #pragma unroll
            for (int n = 0; n < 4; ++n)
                acc[m + 4][n] = __builtin_amdgcn_mfma_f32_16x16x32_bf16(af[m], bf[n], acc[m + 4][n], 0, 0, 0);
        __builtin_amdgcn_s_setprio(0);
        __builtin_amdgcn_s_barrier();
    }

    // ---- epilogue ----
    #pragma unroll
    for (int n = 0; n < 4; ++n) {
        const int col = colTile + wc * 64 + n * 16 + laneRA;
        float bv = 0.f;
        if constexpr (BIASK == 1) bv = inp(bias, bias_off + col, md);
        if constexpr (BIASK == 2) bv = ((const float*)bias)[bias_off + col];
        #pragma unroll
        for (int m = 0; m < 8; ++m) {
            #pragma unroll
            for (int r = 0; r < 4; ++r) {
                const int row = rowTile + wr * 128 + m * 16 + ((lane >> 4) << 2) + r;
                float xv = acc[m][n][r] + bv;
                if constexpr (GELU) xv = 0.5f * xv * (1.f + erff(xv * 0.70710678118654752f));
                const size_t idx = (size_t)row * ldc + col;
                if constexpr (OUTK == 1)      ((u16*)Cv)[idx] = f2b(xv);
                else if constexpr (OUTK == 0) ((float*)Cv)[idx] = xv;
                else {
                    if (md) ((u16*)Cv)[idx] = f2b(xv);
                    else    ((float*)Cv)[idx] = xv;
                }
            }
        }
    }
}

// ---------------- GEMM (m97-style, 4 waves) — small/odd shapes ------------------------
template<int BM, int BN, int WGM, int WGN, int OUTK, bool GELU,
         bool COLMAJ, bool CSKIP, bool CK, int BIASK>
__global__ __launch_bounds__(256)
void gemm_bt(const u16* __restrict__ A, int lda, ll offAo, ll offAi,
             const u16* __restrict__ Bt, int ldb, ll offBo, ll offBi,
             void* __restrict__ Cv, int ldc, ll offCo, ll offCi,
             int HB, int K,
             const void* __restrict__ bias, ll bias_off, float scale,
             const float* __restrict__ r1, const float* __restrict__ r2,
             const int* __restrict__ modeflag)
{
    constexpr int MF = BM / WGM / 16;
    constexpr int NF = BN / WGN / 16;
    static_assert(BM % (WGM * 16) == 0 && BN % (WGN * 16) == 0, "tile/wave mismatch");
    static_assert(WGM * WGN == 4, "4 waves");
    __shared__ __align__(16) u16 sA[BM * 64];
    __shared__ __align__(16) u16 sB[BN * 64];

    const int rowTile = (COLMAJ ? blockIdx.x : blockIdx.y) * BM;
    const int colTile = (COLMAJ ? blockIdx.y : blockIdx.x) * BN;
    if constexpr (CSKIP) {
        if (colTile >= rowTile + BM) return;
    }

    const int md = *modeflag;
    const int z = blockIdx.z;
    const ll zo = z / HB, zi = z % HB;
    const u16* Ab = A + zo * offAo + zi * offAi;
    const u16* Bb = Bt + zo * offBo + zi * offBi;

    const int tid  = threadIdx.x;
    const int lane = tid & 63, wid = tid >> 6;
    const int wr = wid / WGN, wc = wid % WGN;
    const int lr = lane >> 3, lc8 = (lane & 7) << 3;

    f32x4 zero = {0.f, 0.f, 0.f, 0.f};
    f32x4 acc[MF][NF];
    #pragma unroll
    for (int m = 0; m < MF; ++m)
        #pragma unroll
        for (int n = 0; n < NF; ++n) acc[m][n] = zero;

    const int nkt = CK ? ((rowTile + BM) >> 6) : (K >> 6);
    for (int kt = 0; kt < nkt; ++kt) {
        const int k0 = kt << 6;
        #pragma unroll
        for (int i = 0; i < BM / 32; ++i) {
            int c = i * 4 + wid;
            gload16(Ab + (size_t)(rowTile + c * 8 + lr) * lda + k0 + lc8, &sA[c * 512]);
        }
        #pragma unroll
        for (int i = 0; i < BN / 32; ++i) {
            int c = i * 4 + wid;
            gload16(Bb + (size_t)(colTile + c * 8 + lr) * ldb + k0 + lc8, &sB[c * 512]);
        }
        asm volatile("s_waitcnt vmcnt(0)" ::: "memory");
        __syncthreads();
        #pragma unroll
        for (int kk = 0; kk < 2; ++kk) {
            const int ko = kk * 32 + (lane >> 4) * 8;
            bf16x8 af[MF], bfv[NF];
            #pragma unroll
            for (int m = 0; m < MF; ++m)
                af[m] = *(const bf16x8*)&sA[(wr * (BM / WGM) + m * 16 + (lane & 15)) * 64 + ko];
            #pragma unroll
            for (int n = 0; n < NF; ++n)
                bfv[n] = *(const bf16x8*)&sB[(wc * (BN / WGN) + n * 16 + (lane & 15)) * 64 + ko];
            #pragma unroll
            for (int m = 0; m < MF; ++m)
                #pragma unroll
                for (int n = 0; n < NF; ++n)
                    acc[m][n] = __builtin_amdgcn_mfma_f32_16x16x32_bf16(af[m], bfv[n], acc[m][n], 0, 0, 0);
        }
        __syncthreads();
    }

    const ll offC = zo * offCo + zi * offCi;
    #pragma unroll
    for (int m = 0; m < MF; ++m) {
        #pragma unroll
        for (int n = 0; n < NF; ++n) {
            const int col = colTile + wc * (BN / WGN) + n * 16 + (lane & 15);
            float bv = 0.f;
            if constexpr (BIASK == 1) bv = inp(bias, bias_off + col, md);
            if constexpr (BIASK == 2) bv = ((const float*)bias)[bias_off + col];
            #pragma unroll
            for (int r = 0; r < 4; ++r) {
                const int row = rowTile + wr * (BM / WGM) + m * 16 + ((lane >> 4) << 2) + r;
                float xv = acc[m][n][r] * scale + bv;
                if constexpr (GELU) xv = 0.5f * xv * (1.f + erff(xv * 0.70710678118654752f));
                const size_t idx = (size_t)row * ldc + col;
                if (r1) xv += r1[idx];
                if (r2) xv += r2[idx];
                if constexpr (OUTK == 1)      ((u16*)Cv)[offC + idx] = f2b(xv);
                else if constexpr (OUTK == 0) ((float*)Cv)[offC + idx] = xv;
                else {
                    if (md) ((u16*)Cv)[offC + idx] = f2b(xv);
                    else    ((float*)Cv)[offC + idx] = xv;
                }
            }
        }
    }
}

// ------- transpose input weight (bf16 OR f32) -> bf16 ---------------------------------
__global__ __launch_bounds__(256)
void transpose_k(const void* __restrict__ in, u16* __restrict__ out,
                 int R, int C, int ins, int outs,
                 ll base, ll iStride, ll oStride,
                 const int* __restrict__ modeflag)
{
    __shared__ u16 tile[32][33];
    const int md = *modeflag;
    const int z = blockIdx.z;
    const ll ioff = base + (ll)z * iStride;
    u16* op = out + (ll)z * oStride;
    const int tx = threadIdx.x & 31, ty = threadIdx.x >> 5;
    const int c0 = blockIdx.x * 32, r0 = blockIdx.y * 32;
    #pragma unroll
    for (int i = 0; i < 32; i += 8) {
        int r = r0 + ty + i, c = c0 + tx;
        if (r < R && c < C) tile[ty + i][tx] = f2b(inp(in, ioff + (ll)r * ins + c, md));
    }
    __syncthreads();
    #pragma unroll
    for (int i = 0; i < 32; i += 8) {
        int c = c0 + ty + i, r = r0 + tx;
        if (c < C && r < R) op[(size_t)c * outs + r] = tile[tx][ty + i];
    }
}

// ------- fused per-layer weight transposes: QKV + O + In + Out in ONE launch ----------
__global__ __launch_bounds__(256)
void transw_k(const void* __restrict__ Qw, const void* __restrict__ Kw,
              const void* __restrict__ Vw, const void* __restrict__ Ow,
              const void* __restrict__ Inw, const void* __restrict__ Outw,
              u16* __restrict__ WqkvT, u16* __restrict__ WoT,
              u16* __restrict__ WinT, u16* __restrict__ WoutT,
              int l, const int* __restrict__ modeflag)
{
    __shared__ u16 tile[32][33];
    const int md = *modeflag;
    const int b = blockIdx.x;
    const void* in; u16* out; int ins, outs, tx_, ty_; ll ibase;
    if (b < 1728) {                       // QKV: 3 segs x 12 heads x 48 tiles (2x24)
        const int seg = b / 576, rem = b % 576, hd = rem / 48, tt = rem % 48;
        in = seg == 0 ? Qw : (seg == 1 ? Kw : Vw);
        ibase = (ll)l * cH * cD * cDH + (ll)hd * cD * cDH;
        out = WqkvT + (ll)seg * cD * cD + (ll)hd * cDH * cD;
        ins = cDH; outs = cD; tx_ = tt % 2; ty_ = tt / 2;
    } else if (b < 2304) {                // O: 24 x 24
        const int tt = b - 1728;
        in = Ow; ibase = (ll)l * cD * cD; out = WoT;
        ins = cD; outs = cD; tx_ = tt % 24; ty_ = tt / 24;
    } else if (b < 4608) {                // In: 96 x 24
        const int tt = b - 2304;
        in = Inw; ibase = (ll)l * cD * cM; out = WinT;
        ins = cM; outs = cD; tx_ = tt % 96; ty_ = tt / 96;
    } else {                              // Out: 24 x 96
        const int tt = b - 4608;
        in = Outw; ibase = (ll)l * cM * cD; out = WoutT;
        ins = cD; outs = cM; tx_ = tt % 24; ty_ = tt / 24;
    }
    const int tx = threadIdx.x & 31, ty = threadIdx.x >> 5;
    const int c0 = tx_ * 32, r0 = ty_ * 32;
    #pragma unroll
    for (int i = 0; i < 32; i += 8)
        tile[ty + i][tx] = f2b(inp(in, ibase + (ll)(r0 + ty + i) * ins + c0 + tx, md));
    __syncthreads();
    #pragma unroll
    for (int i = 0; i < 32; i += 8)
        out[(size_t)(c0 + ty + i) * outs + (r0 + tx)] = tile[tx][ty + i];
}

// ---- bf16 transpose for internal V slice (qkv cols) ----------------------------------
__global__ __launch_bounds__(256)
void transpose_b_k(const u16* __restrict__ in, u16* __restrict__ out,
                   int R, int C, int ins, int outs,
                   ll iOo, ll iOi, ll oOo, ll oOi, int HB)
{
    __shared__ u16 tile[32][33];
    const int z = blockIdx.z;
    const u16* ip = in  + (ll)(z / HB) * iOo + (ll)(z % HB) * iOi;
    u16*       op = out + (ll)(z / HB) * oOo + (ll)(z % HB) * oOi;
    const int tx = threadIdx.x & 31, ty = threadIdx.x >> 5;
    const int c0 = blockIdx.x * 32, r0 = blockIdx.y * 32;
    #pragma unroll
    for (int i = 0; i < 32; i += 8) {
        int r = r0 + ty + i, c = c0 + tx;
        if (r < R && c < C) tile[ty + i][tx] = ip[(size_t)r * ins + c];
    }
    __syncthreads();
    #pragma unroll
    for (int i = 0; i < 32; i += 8) {
        int c = c0 + ty + i, r = r0 + tx;
        if (c < C && r < R) op[(size_t)c * outs + r] = tile[tx][ty + i];
    }
}

// ---------------- embedding: res = E[x] + P (f32 out) ---------------------------------
__global__ __launch_bounds__(192)
void embed_k(const int* __restrict__ x, const void* __restrict__ E,
             const void* __restrict__ P, float* __restrict__ res,
             const int* __restrict__ modeflag)
{
    const int md = *modeflag;
    const int tok = blockIdx.x, t = threadIdx.x;
    const int s = tok & (cS - 1);
    const ll  eb = (ll)x[tok] * cD, pb = (ll)s * cD;
    float4 o;
    o.x = inp(E, eb + t * 4 + 0, md) + inp(P, pb + t * 4 + 0, md);
    o.y = inp(E, eb + t * 4 + 1, md) + inp(P, pb + t * 4 + 1, md);
    o.z = inp(E, eb + t * 4 + 2, md) + inp(P, pb + t * 4 + 2, md);
    o.w = inp(E, eb + t * 4 + 3, md) + inp(P, pb + t * 4 + 3, md);
    ((float4*)(res + (size_t)tok * cD))[t] = o;
}

// ---------------- layernorm (unbiased std, ddof=1), f32 in, bf16 out ------------------
__global__ __launch_bounds__(192)
void ln_k(const float* __restrict__ in, const void* __restrict__ w,
          const void* __restrict__ b, ll wb_off, u16* __restrict__ out,
          const int* __restrict__ modeflag)
{
    __shared__ float sm[8];
    const int md = *modeflag;
    const int row = blockIdx.x, t = threadIdx.x;
    const float4 x = ((const float4*)(in + (size_t)row * cD))[t];
    float s = wave_sum(x.x + x.y + x.z + x.w);
    const int lane = t & 63, wv = t >> 6;
    if (!lane) sm[wv] = s;
    __syncthreads();
    const float mu = (sm[0] + sm[1] + sm[2]) * (1.f / (float)cD);
    const float dx = x.x - mu, dy = x.y - mu, dz = x.z - mu, dw = x.w - mu;
    float ss = wave_sum(dx * dx + dy * dy + dz * dz + dw * dw);
    if (!lane) sm[4 + wv] = ss;
    __syncthreads();
    const float var = (sm[4] + sm[5] + sm[6]) * (1.f / (float)(cD - 1));
    const float rs  = 1.f / sqrtf(var);
    const ll o4 = wb_off + (ll)t * 4;
    ushort4 o;
    o.x = f2b(inp(w, o4 + 0, md) * (dx * rs) + inp(b, o4 + 0, md));
    o.y = f2b(inp(w, o4 + 1, md) * (dy * rs) + inp(b, o4 + 1, md));
    o.z = f2b(inp(w, o4 + 2, md) * (dz * rs) + inp(b, o4 + 2, md));
    o.w = f2b(inp(w, o4 + 3, md) * (dw * rs) + inp(b, o4 + 3, md));
    ((ushort4*)(out + (size_t)row * cD))[t] = o;
}

// ---------------- causal softmax, in-place on bf16 [rows=BH*S][S] ----------------------
__global__ __launch_bounds__(256)
void softmax_k(u16* __restrict__ p)
{
    __shared__ float sm[8];
    const int row = blockIdx.x;
    const int q = row & (cS - 1);
    u16* pr = p + (size_t)row * cS;
    const int t = threadIdx.x;
    const int j0 = t * 4;
    ushort4 v = {0, 0, 0, 0};
    if (j0 <= q) v = ((const ushort4*)pr)[t];
    float x0 = (j0 + 0 <= q) ? b2f(v.x) : -100000.f;
    float x1 = (j0 + 1 <= q) ? b2f(v.y) : -100000.f;
    float x2 = (j0 + 2 <= q) ? b2f(v.z) : -100000.f;
    float x3 = (j0 + 3 <= q) ? b2f(v.w) : -100000.f;
    float mx = wave_max(fmaxf(fmaxf(x0, x1), fmaxf(x2, x3)));
    const int lane = t & 63, wv = t >> 6;
    if (!lane) sm[wv] = mx;
    __syncthreads();
    const float MX = fmaxf(fmaxf(sm[0], sm[1]), fmaxf(sm[2], sm[3]));
    const float e0 = expf(x0 - MX), e1 = expf(x1 - MX), e2 = expf(x2 - MX), e3 = expf(x3 - MX);
    float ssum = wave_sum(e0 + e1 + e2 + e3);
    if (!lane) sm[4 + wv] = ssum;
    __syncthreads();
    const float inv = 1.f / (sm[4] + sm[5] + sm[6] + sm[7]);
    ushort4 o;
    o.x = f2b(e0 * inv); o.y = f2b(e1 * inv); o.z = f2b(e2 * inv); o.w = f2b(e3 * inv);
    ((ushort4*)pr)[t] = o;
}

// =====================================================================================
extern "C" void kernel_launch(void* const* d_in, const int* in_sizes, int n_in,
                              void* d_out, int out_size, void* d_ws, size_t ws_size,
                              hipStream_t stream)
{
    (void)in_sizes; (void)n_in; (void)out_size;
    const int*  x     = (const int*)d_in[0];
    const void* E_w   = d_in[1];
    const void* P_w   = d_in[2];
    const void* ln1_w = d_in[3];
    const void* ln1_b = d_in[4];
    const void* Q_w   = d_in[5];
    const void* Q_b   = d_in[6];
    const void* K_w   = d_in[7];
    const void* K_b   = d_in[8];
    const void* V_w   = d_in[9];
    const void* V_b   = d_in[10];
    const void* O_w   = d_in[11];
    const void* O_b   = d_in[12];
    const void* ln2_w = d_in[13];
    const void* ln2_b = d_in[14];
    const void* In_w  = d_in[15];
    const void* In_b  = d_in[16];
    const void* Out_w = d_in[17];
    const void* Out_b = d_in[18];
    const void* lnf_w = d_in[19];
    const void* lnf_b = d_in[20];
    const void* U_w   = d_in[21];
    const void* U_b   = d_in[22];

    // ---- workspace carve with aliasing (~99 MB) ----
    char* wp = (char*)d_ws;
    auto carve = [&](size_t bytes) { char* r = wp; wp += (bytes + 255) & ~(size_t)255; return r; };
    int*   modeflag = (int*)carve(256);
    float* biasQKV  = (float*)carve((size_t)cL * cQKV * 4);
    float* res   = (float*)carve((size_t)cT * cD * 4);
    float* resat = (float*)carve((size_t)cT * cD * 4);
    u16* h     = (u16*)carve((size_t)cT * cD * 2);
    u16* attnb = (u16*)carve((size_t)cT * cD * 2);
    u16* vt    = (u16*)carve((size_t)cT * cD * 2);
    u16* qkv   = (u16*)carve((size_t)cT * cM * 2);       // aliased by mlpb
    u16* mlpb  = qkv;
    u16* WqkvT = (u16*)carve((size_t)cQKV * cD * 2);
    u16* WoT   = (u16*)carve((size_t)cD * cD * 2);
    u16* WinT  = (u16*)carve((size_t)cD * cM * 2);
    u16* WoutT = (u16*)carve((size_t)cD * cM * 2);
    u16* pbuf  = (u16*)carve((size_t)cBH * cS * cS * 2);
    u16* WuT   = pbuf;                                   // alias (pbuf dead after layers)

    if (ws_size && (size_t)(wp - (char*)d_ws) > ws_size) return;  // tripwire

    detect_k<<<1, 64, 0, stream>>>((const uint*)E_w, modeflag);
    packbias_k<<<(cL * cQKV) / 256, 256, 0, stream>>>(Q_b, K_b, V_b, biasQKV, modeflag);
    embed_k<<<cT, 192, 0, stream>>>(x, E_w, P_w, res, modeflag);

    for (int l = 0; l < cL; ++l) {
        // fused weight transposes for this layer (1 launch)
        transw_k<<<6912, 256, 0, stream>>>(Q_w, K_w, V_w, O_w, In_w, Out_w,
                                           WqkvT, WoT, WinT, WoutT, l, modeflag);

        // LN1
        ln_k<<<cT, 192, 0, stream>>>(res, ln1_w, ln1_b, (ll)l * cD, h, modeflag);

        // fused QKV projection (gemm_bt 128^2, 288 blocks): [2048,768] @ [2304,768]^T
        gemm_bt<128, 128, 2, 2, 1, false, true, false, false, 2>
            <<<dim3(cT / 128, cQKV / 128, 1), 256, 0, stream>>>(
            h, cD, 0, 0, WqkvT, cD, 0, 0, qkv, cQKV, 0, 0, 1, cD,
            biasQKV, (ll)l * cQKV, 1.f, nullptr, nullptr, modeflag);

        // V slice -> vt [B,H,DH,S]
        transpose_b_k<<<dim3(2, cS / 32, cBH), 256, 0, stream>>>(
            qkv + 2 * cD, vt, cS, cDH, cQKV, cS,
            (ll)cS * cQKV, cDH, (ll)cH * cDH * cS, (ll)cDH * cS, cH);

        // logits = Q K^T * 1/8, batched over (b,h), causal tile skip
        gemm_bt<128, 128, 2, 2, 1, false, false, true, false, 0>
            <<<dim3(8, 8, cBH), 256, 0, stream>>>(
            qkv, cQKV, (ll)cS * cQKV, cDH,
            qkv + cD, cQKV, (ll)cS * cQKV, cDH,
            pbuf, cS, (ll)cH * cS * cS, (ll)cS * cS,
            cH, cDH, nullptr, 0, 0.125f, nullptr, nullptr, modeflag);

        softmax_k<<<cBH * cS, 256, 0, stream>>>(pbuf);

        // attn = P V, batched, causal K-limit
        gemm_bt<128, 64, 4, 1, 1, false, false, false, true, 0>
            <<<dim3(1, 8, cBH), 256, 0, stream>>>(
            pbuf, cS, (ll)cH * cS * cS, (ll)cS * cS,
            vt, cS, (ll)cH * cDH * cS, (ll)cDH * cS,
            attnb, cD, (ll)cS * cD, cDH,
            cH, cS, nullptr, 0, 1.f, nullptr, nullptr, modeflag);

        // O projection + residual -> resat (f32)
        gemm_bt<128, 128, 2, 2, 0, false, true, false, false, 1>
            <<<dim3(cT / 128, cD / 128, 1), 256, 0, stream>>>(
            attnb, cD, 0, 0, WoT, cD, 0, 0, resat, cD, 0, 0, 1, cD,
            O_b, (ll)l * cD, 1.f, res, nullptr, modeflag);

        // LN2
        ln_k<<<cT, 192, 0, stream>>>(resat, ln2_w, ln2_b, (ll)l * cD, h, modeflag);

        // MLP in (gemm_bt 128^2, 384 blocks): gelu(h @ Win + bIn)
        gemm_bt<128, 128, 2, 2, 1, true, true, false, false, 1>
            <<<dim3(cT / 128, cM / 128, 1), 256, 0, stream>>>(
            h, cD, 0, 0, WinT, cD, 0, 0, mlpb, cM, 0, 0, 1, cD,
            In_b, (ll)l * cM, 1.f, nullptr, nullptr, modeflag);

        // MLP out + double residual (64^2 tiles -> 384 blocks, drains overlap across
        // resident blocks at K=3072): res = res + resat + (m @ Wout + bOut)
        gemm_bt<64, 64, 2, 2, 0, false, true, false, false, 1>
            <<<dim3(cT / 64, cD / 64, 1), 256, 0, stream>>>(
            mlpb, cM, 0, 0, WoutT, cM, 0, 0, res, cD, 0, 0, 1, cM,
            Out_b, (ll)l * cD, 1.f, res, resat, modeflag);
    }

    // unembed weight transpose (WuT aliases pbuf), final LN, unembed (gemm256 + T1)
    transpose_k<<<dim3(cV / 32, cD / 32, 1), 256, 0, stream>>>(
        U_w, WuT, cD, cV, cV, cD, 0, 0, 0, modeflag);
    ln_k<<<cT, 192, 0, stream>>>(res, lnf_w, lnf_b, 0, h, modeflag);
    gemm256<2, false, 1><<<dim3(cT / 256, cV / 256, 1), 512, 0, stream>>>(
        h, cD, WuT, cD, d_out, cV, cD, U_b, 0, modeflag);
}

// Round 7
// 1194.934 us; speedup vs baseline: 1.3561x; 1.0952x over previous
//
#include <hip/hip_runtime.h>

using uint = unsigned int;
using u16  = unsigned short;
using ll   = long long;

constexpr int cL = 4, cH = 12, cDH = 64, cD = 768, cM = 3072, cV = 32000, cS = 1024, cB = 2;
constexpr int cT  = cB * cS;   // 2048 tokens
constexpr int cBH = cB * cH;   // 24
constexpr int cQKV = 3 * cD;   // 2304

using bf16x8 = __bf16 __attribute__((ext_vector_type(8)));
using f32x4  = float  __attribute__((ext_vector_type(4)));

__device__ __forceinline__ float b2f(u16 u) {
    union { uint i; float f; } v; v.i = ((uint)u) << 16; return v.f;
}
__device__ __forceinline__ u16 f2b(float f) {
    union { float f; uint i; } v; v.f = f;
    uint u = v.i;
    return (u16)((u + 0x7fffu + ((u >> 16) & 1u)) >> 16);   // RNE
}
// read input element `idx` as float, per mode (1 = bf16, 0 = f32)
__device__ __forceinline__ float inp(const void* p, ll idx, int md) {
    return md ? b2f(((const u16*)p)[idx]) : ((const float*)p)[idx];
}
__device__ __forceinline__ float wave_sum(float v) {
    #pragma unroll
    for (int m = 32; m; m >>= 1) v += __shfl_xor(v, m);
    return v;
}
__device__ __forceinline__ float wave_max(float v) {
    #pragma unroll
    for (int m = 32; m; m >>= 1) v = fmaxf(v, __shfl_xor(v, m));
    return v;
}
__device__ __forceinline__ void gload16(const u16* g, u16* l) {
    __builtin_amdgcn_global_load_lds(
        (const __attribute__((address_space(1))) uint*)g,
        (__attribute__((address_space(3))) uint*)l,
        16, 0, 0);
}

// ---------------- dtype detector ------------------------------------------------------
__global__ void detect_k(const uint* __restrict__ e, int* __restrict__ flag)
{
    const int l = threadIdx.x;
    int hits = 0;
    #pragma unroll
    for (int i = 0; i < 4; ++i) {
        uint w  = e[l * 4 + i];
        uint ex = (w >> 7) & 0xffu;
        hits += (ex >= 100u && ex <= 126u) ? 1 : 0;
    }
    float s = wave_sum((float)hits);
    if (l == 0) *flag = (s >= 128.f) ? 1 : 0;   // 1 = bf16 inputs, 0 = f32 inputs
}

// ---------------- pack QKV biases -> f32 [L][2304] ------------------------------------
__global__ __launch_bounds__(256)
void packbias_k(const void* __restrict__ Qb, const void* __restrict__ Kb,
                const void* __restrict__ Vb, float* __restrict__ out,
                const int* __restrict__ modeflag)
{
    const int md = *modeflag;
    const int i = blockIdx.x * 256 + threadIdx.x;   // i < L*2304
    const int l = i / cQKV, c = i % cQKV;
    float v;
    if (c < cD)           v = inp(Qb, (ll)l * cD + c, md);
    else if (c < 2 * cD)  v = inp(Kb, (ll)l * cD + c - cD, md);
    else                  v = inp(Vb, (ll)l * cD + c - 2 * cD, md);
    out[i] = v;
}

// =============== gemm256: 8-wave 256x256 tile, BK=32, tri-buffered pipeline ===========
// C = A[M,K] * Bt[N,K]^T + bias; OUTK: 0=f32, 1=bf16, 2=dynamic; BIASK: 0 none/1 inp/2 f32
// T1 bijective XCD swizzle; T2 both-sides LDS swizzle; T3/T4 counted vmcnt(4); T5 setprio.
// C stores are non-temporal (output never re-read; avoid write-allocate/RFO).
template<int OUTK, bool GELU, int BIASK>
__global__ __launch_bounds__(512, 1)
void gemm256(const u16* __restrict__ A, int lda,
             const u16* __restrict__ Bt, int ldb,
             void* __restrict__ Cv, int ldc, int K,
             const void* __restrict__ bias, ll bias_off,
             const int* __restrict__ modeflag)
{
    __shared__ __align__(16) u16 lds[3 * 16384];   // 3 bufs x (A 8192 + B 8192) u16

    // T1: bijective XCD-aware remap of the linear block id (8 XCDs, round-robin dispatch)
    const int nwg = gridDim.x * gridDim.y;
    const int lin = blockIdx.y * gridDim.x + blockIdx.x;
    const int q8 = nwg >> 3, r8 = nwg & 7;
    const int xcd = lin & 7, idx = lin >> 3;
    const int n_  = (xcd < r8 ? xcd * (q8 + 1) : r8 * (q8 + 1) + (xcd - r8) * q8) + idx;
    const int rowTile = (n_ % gridDim.x) * 256;
    const int colTile = (n_ / gridDim.x) * 256;

    const int md = *modeflag;
    const int tid  = threadIdx.x;
    const int lane = tid & 63, wid = tid >> 6;
    const int wr = wid >> 2, wc = wid & 3;          // 2 x 4 waves, per-wave 128x64
    const int rs = tid >> 2, gs = tid & 3;          // staging row/16B-group
    const int nt = K >> 5;                          // BK = 32

    auto stageA = [&](int t, int h) {               // half h: rows [h*128, h*128+128)
        const int r = h * 128 + rs;
        const u16* src = A + (size_t)(rowTile + r) * lda + t * 32 + ((gs ^ ((r >> 1) & 3)) << 3);
        gload16(src, &lds[(t % 3) * 16384 + h * 4096 + wid * 512]);
    };
    auto stageB = [&](int t, int h) {
        const int r = h * 128 + rs;
        const u16* src = Bt + (size_t)(colTile + r) * ldb + t * 32 + ((gs ^ ((r >> 1) & 3)) << 3);
        gload16(src, &lds[(t % 3) * 16384 + 8192 + h * 4096 + wid * 512]);
    };

    f32x4 acc[8][4];
    #pragma unroll
    for (int m = 0; m < 8; ++m)
        #pragma unroll
        for (int n = 0; n < 4; ++n) acc[m][n] = f32x4{0.f, 0.f, 0.f, 0.f};

    // prologue: stage tiles 0 and 1
    stageA(0, 0); stageB(0, 0); stageA(0, 1); stageB(0, 1);
    if (nt > 1) { stageA(1, 0); stageB(1, 0); stageA(1, 1); stageB(1, 1); }
    if (nt > 1) asm volatile("s_waitcnt vmcnt(4)" ::: "memory");
    else        asm volatile("s_waitcnt vmcnt(0)" ::: "memory");
    __builtin_amdgcn_s_barrier();

    const int laneRA = lane & 15, cb16 = lane >> 4;
    for (int t = 0; t < nt; ++t) {
        const int bb = (t % 3) * 16384;
        bf16x8 bf[4], af[4];
        // ---- phase 0: B frags + A frags m=0..3; stage (t+2) half 0 ----
        #pragma unroll
        for (int n = 0; n < 4; ++n) {
            const int rb = wc * 64 + n * 16 + laneRA;
            bf[n] = *(const bf16x8*)&lds[bb + 8192 + rb * 32 + ((cb16 ^ ((rb >> 1) & 3)) << 3)];
        }
        #pragma unroll
        for (int m = 0; m < 4; ++m) {
            const int ra = wr * 128 + m * 16 + laneRA;
            af[m] = *(const bf16x8*)&lds[bb + ra * 32 + ((cb16 ^ ((ra >> 1) & 3)) << 3)];
        }
        if (t + 2 < nt) { stageA(t + 2, 0); stageB(t + 2, 0); }
        __builtin_amdgcn_s_barrier();
        asm volatile("s_waitcnt lgkmcnt(0)" ::: "memory");
        __builtin_amdgcn_sched_barrier(0);
        __builtin_amdgcn_s_setprio(1);
        #pragma unroll
        for (int m = 0; m < 4; ++m)
            #pragma unroll
            for (int n = 0; n < 4; ++n)
                acc[m][n] = __builtin_amdgcn_mfma_f32_16x16x32_bf16(af[m], bf[n], acc[m][n], 0, 0, 0);
        __builtin_amdgcn_s_setprio(0);
        __builtin_amdgcn_s_barrier();
        // ---- phase 1: A frags m=4..7; stage (t+2) half 1; counted vmcnt ----
        #pragma unroll
        for (int m = 0; m < 4; ++m) {
            const int ra = wr * 128 + (m + 4) * 16 + laneRA;
            af[m] = *(const bf16x8*)&lds[bb + ra * 32 + ((cb16 ^ ((ra >> 1) & 3)) << 3)];
        }
        if (t + 2 < nt) { stageA(t + 2, 1); stageB(t + 2, 1); }
        if (t + 2 < nt)      asm volatile("s_waitcnt vmcnt(4)" ::: "memory");
        else if (t + 1 < nt) asm volatile("s_waitcnt vmcnt(0)" ::: "memory");
        __builtin_amdgcn_s_barrier();
        asm volatile("s_waitcnt lgkmcnt(0)" ::: "memory");
        __builtin_amdgcn_sched_barrier(0);
        __builtin_amdgcn_s_setprio(1);
        #pragma unroll
        for (int m = 0; m < 4; ++m)
            #pragma unroll
            for (int n = 0; n < 4; ++n)
                acc[m + 4][n] = __builtin_amdgcn_mfma_f32_16x16x32_bf16(af[m], bf[n], acc[m + 4][n], 0, 0, 0);
        __builtin_amdgcn_s_setprio(0);
        __builtin_amdgcn_s_barrier();
    }

    // ---- epilogue (non-temporal stores) ----
    #pragma unroll
    for (int n = 0; n < 4; ++n) {
        const int col = colTile + wc * 64 + n * 16 + laneRA;
        float bv = 0.f;
        if constexpr (BIASK == 1) bv = inp(bias, bias_off + col, md);
        if constexpr (BIASK == 2) bv = ((const float*)bias)[bias_off + col];
        #pragma unroll
        for (int m = 0; m < 8; ++m) {
            #pragma unroll
            for (int r = 0; r < 4; ++r) {
                const int row = rowTile + wr * 128 + m * 16 + ((lane >> 4) << 2) + r;
                float xv = acc[m][n][r] + bv;
                if constexpr (GELU) xv = 0.5f * xv * (1.f + erff(xv * 0.70710678118654752f));
                const size_t idx = (size_t)row * ldc + col;
                if constexpr (OUTK == 1)
                    __builtin_nontemporal_store(f2b(xv), &((u16*)Cv)[idx]);
                else if constexpr (OUTK == 0)
                    __builtin_nontemporal_store(xv, &((float*)Cv)[idx]);
                else {
                    if (md) __builtin_nontemporal_store(f2b(xv), &((u16*)Cv)[idx]);
                    else    __builtin_nontemporal_store(xv, &((float*)Cv)[idx]);
                }
            }
        }
    }
}

// ---------------- GEMM (m97-style, 4 waves) — small/odd shapes ------------------------
// CSKIP: causal QK^T — compact triangular grid, blockIdx.x = tri-index (BM must == BN)
template<int BM, int BN, int WGM, int WGN, int OUTK, bool GELU,
         bool COLMAJ, bool CSKIP, bool CK, int BIASK>
__global__ __launch_bounds__(256)
void gemm_bt(const u16* __restrict__ A, int lda, ll offAo, ll offAi,
             const u16* __restrict__ Bt, int ldb, ll offBo, ll offBi,
             void* __restrict__ Cv, int ldc, ll offCo, ll offCi,
             int HB, int K,
             const void* __restrict__ bias, ll bias_off, float scale,
             const float* __restrict__ r1, const float* __restrict__ r2,
             const int* __restrict__ modeflag)
{
    constexpr int MF = BM / WGM / 16;
    constexpr int NF = BN / WGN / 16;
    static_assert(BM % (WGM * 16) == 0 && BN % (WGN * 16) == 0, "tile/wave mismatch");
    static_assert(WGM * WGN == 4, "4 waves");
    __shared__ __align__(16) u16 sA[BM * 64];
    __shared__ __align__(16) u16 sB[BN * 64];

    int rowTile, colTile;
    if constexpr (CSKIP) {
        // triangular decode: tiles (r,c), c <= r
        const int bi = blockIdx.x;
        int r = (int)((sqrtf(8.f * bi + 1.f) - 1.f) * 0.5f);
        while ((r + 1) * (r + 2) / 2 <= bi) ++r;
        while (r * (r + 1) / 2 > bi) --r;
        rowTile = r * BM;
        colTile = (bi - r * (r + 1) / 2) * BN;
    } else {
        rowTile = (COLMAJ ? blockIdx.x : blockIdx.y) * BM;
        colTile = (COLMAJ ? blockIdx.y : blockIdx.x) * BN;
    }

    const int md = *modeflag;
    const int z = blockIdx.z;
    const ll zo = z / HB, zi = z % HB;
    const u16* Ab = A + zo * offAo + zi * offAi;
    const u16* Bb = Bt + zo * offBo + zi * offBi;

    const int tid  = threadIdx.x;
    const int lane = tid & 63, wid = tid >> 6;
    const int wr = wid / WGN, wc = wid % WGN;
    const int lr = lane >> 3, lc8 = (lane & 7) << 3;

    f32x4 zero = {0.f, 0.f, 0.f, 0.f};
    f32x4 acc[MF][NF];
    #pragma unroll
    for (int m = 0; m < MF; ++m)
        #pragma unroll
        for (int n = 0; n < NF; ++n) acc[m][n] = zero;

    const int nkt = CK ? ((rowTile + BM) >> 6) : (K >> 6);
    for (int kt = 0; kt < nkt; ++kt) {
        const int k0 = kt << 6;
        #pragma unroll
        for (int i = 0; i < BM / 32; ++i) {
            int c = i * 4 + wid;
            gload16(Ab + (size_t)(rowTile + c * 8 + lr) * lda + k0 + lc8, &sA[c * 512]);
        }
        #pragma unroll
        for (int i = 0; i < BN / 32; ++i) {
            int c = i * 4 + wid;
            gload16(Bb + (size_t)(colTile + c * 8 + lr) * ldb + k0 + lc8, &sB[c * 512]);
        }
        asm volatile("s_waitcnt vmcnt(0)" ::: "memory");
        __syncthreads();
        #pragma unroll
        for (int kk = 0; kk < 2; ++kk) {
            const int ko = kk * 32 + (lane >> 4) * 8;
            bf16x8 af[MF], bfv[NF];
            #pragma unroll
            for (int m = 0; m < MF; ++m)
                af[m] = *(const bf16x8*)&sA[(wr * (BM / WGM) + m * 16 + (lane & 15)) * 64 + ko];
            #pragma unroll
            for (int n = 0; n < NF; ++n)
                bfv[n] = *(const bf16x8*)&sB[(wc * (BN / WGN) + n * 16 + (lane & 15)) * 64 + ko];
            #pragma unroll
            for (int m = 0; m < MF; ++m)
                #pragma unroll
                for (int n = 0; n < NF; ++n)
                    acc[m][n] = __builtin_amdgcn_mfma_f32_16x16x32_bf16(af[m], bfv[n], acc[m][n], 0, 0, 0);
        }
        __syncthreads();
    }

    const ll offC = zo * offCo + zi * offCi;
    #pragma unroll
    for (int m = 0; m < MF; ++m) {
        #pragma unroll
        for (int n = 0; n < NF; ++n) {
            const int col = colTile + wc * (BN / WGN) + n * 16 + (lane & 15);
            float bv = 0.f;
            if constexpr (BIASK == 1) bv = inp(bias, bias_off + col, md);
            if constexpr (BIASK == 2) bv = ((const float*)bias)[bias_off + col];
            #pragma unroll
            for (int r = 0; r < 4; ++r) {
                const int row = rowTile + wr * (BM / WGM) + m * 16 + ((lane >> 4) << 2) + r;
                float xv = acc[m][n][r] * scale + bv;
                if constexpr (GELU) xv = 0.5f * xv * (1.f + erff(xv * 0.70710678118654752f));
                const size_t idx = (size_t)row * ldc + col;
                if (r1) xv += r1[idx];
                if (r2) xv += r2[idx];
                if constexpr (OUTK == 1)      ((u16*)Cv)[offC + idx] = f2b(xv);
                else if constexpr (OUTK == 0) ((float*)Cv)[offC + idx] = xv;
                else {
                    if (md) ((u16*)Cv)[offC + idx] = f2b(xv);
                    else    ((float*)Cv)[offC + idx] = xv;
                }
            }
        }
    }
}

// ------- transpose input weight (bf16 OR f32) -> bf16 ---------------------------------
__global__ __launch_bounds__(256)
void transpose_k(const void* __restrict__ in, u16* __restrict__ out,
                 int R, int C, int ins, int outs,
                 ll base, ll iStride, ll oStride,
                 const int* __restrict__ modeflag)
{
    __shared__ u16 tile[32][33];
    const int md = *modeflag;
    const int z = blockIdx.z;
    const ll ioff = base + (ll)z * iStride;
    u16* op = out + (ll)z * oStride;
    const int tx = threadIdx.x & 31, ty = threadIdx.x >> 5;
    const int c0 = blockIdx.x * 32, r0 = blockIdx.y * 32;
    #pragma unroll
    for (int i = 0; i < 32; i += 8) {
        int r = r0 + ty + i, c = c0 + tx;
        if (r < R && c < C) tile[ty + i][tx] = f2b(inp(in, ioff + (ll)r * ins + c, md));
    }
    __syncthreads();
    #pragma unroll
    for (int i = 0; i < 32; i += 8) {
        int c = c0 + ty + i, r = r0 + tx;
        if (c < C && r < R) op[(size_t)c * outs + r] = tile[tx][ty + i];
    }
}

// ------- fused per-layer weight transposes: QKV + O + In + Out in ONE launch ----------
__global__ __launch_bounds__(256)
void transw_k(const void* __restrict__ Qw, const void* __restrict__ Kw,
              const void* __restrict__ Vw, const void* __restrict__ Ow,
              const void* __restrict__ Inw, const void* __restrict__ Outw,
              u16* __restrict__ WqkvT, u16* __restrict__ WoT,
              u16* __restrict__ WinT, u16* __restrict__ WoutT,
              int l, const int* __restrict__ modeflag)
{
    __shared__ u16 tile[32][33];
    const int md = *modeflag;
    const int b = blockIdx.x;
    const void* in; u16* out; int ins, outs, tx_, ty_; ll ibase;
    if (b < 1728) {                       // QKV: 3 segs x 12 heads x 48 tiles (2x24)
        const int seg = b / 576, rem = b % 576, hd = rem / 48, tt = rem % 48;
        in = seg == 0 ? Qw : (seg == 1 ? Kw : Vw);
        ibase = (ll)l * cH * cD * cDH + (ll)hd * cD * cDH;
        out = WqkvT + (ll)seg * cD * cD + (ll)hd * cDH * cD;
        ins = cDH; outs = cD; tx_ = tt % 2; ty_ = tt / 2;
    } else if (b < 2304) {                // O: 24 x 24
        const int tt = b - 1728;
        in = Ow; ibase = (ll)l * cD * cD; out = WoT;
        ins = cD; outs = cD; tx_ = tt % 24; ty_ = tt / 24;
    } else if (b < 4608) {                // In: 96 x 24
        const int tt = b - 2304;
        in = Inw; ibase = (ll)l * cD * cM; out = WinT;
        ins = cM; outs = cD; tx_ = tt % 96; ty_ = tt / 96;
    } else {                              // Out: 24 x 96
        const int tt = b - 4608;
        in = Outw; ibase = (ll)l * cM * cD; out = WoutT;
        ins = cD; outs = cM; tx_ = tt % 24; ty_ = tt / 24;
    }
    const int tx = threadIdx.x & 31, ty = threadIdx.x >> 5;
    const int c0 = tx_ * 32, r0 = ty_ * 32;
    #pragma unroll
    for (int i = 0; i < 32; i += 8)
        tile[ty + i][tx] = f2b(inp(in, ibase + (ll)(r0 + ty + i) * ins + c0 + tx, md));
    __syncthreads();
    #pragma unroll
    for (int i = 0; i < 32; i += 8)
        out[(size_t)(c0 + ty + i) * outs + (r0 + tx)] = tile[tx][ty + i];
}

// ---- bf16 transpose for internal V slice (qkv cols) ----------------------------------
__global__ __launch_bounds__(256)
void transpose_b_k(const u16* __restrict__ in, u16* __restrict__ out,
                   int R, int C, int ins, int outs,
                   ll iOo, ll iOi, ll oOo, ll oOi, int HB)
{
    __shared__ u16 tile[32][33];
    const int z = blockIdx.z;
    const u16* ip = in  + (ll)(z / HB) * iOo + (ll)(z % HB) * iOi;
    u16*       op = out + (ll)(z / HB) * oOo + (ll)(z % HB) * oOi;
    const int tx = threadIdx.x & 31, ty = threadIdx.x >> 5;
    const int c0 = blockIdx.x * 32, r0 = blockIdx.y * 32;
    #pragma unroll
    for (int i = 0; i < 32; i += 8) {
        int r = r0 + ty + i, c = c0 + tx;
        if (r < R && c < C) tile[ty + i][tx] = ip[(size_t)r * ins + c];
    }
    __syncthreads();
    #pragma unroll
    for (int i = 0; i < 32; i += 8) {
        int c = c0 + ty + i, r = r0 + tx;
        if (c < C && r < R) op[(size_t)c * outs + r] = tile[tx][ty + i];
    }
}

// ---------------- embedding: res = E[x] + P (f32 out) ---------------------------------
__global__ __launch_bounds__(192)
void embed_k(const int* __restrict__ x, const void* __restrict__ E,
             const void* __restrict__ P, float* __restrict__ res,
             const int* __restrict__ modeflag)
{
    const int md = *modeflag;
    const int tok = blockIdx.x, t = threadIdx.x;
    const int s = tok & (cS - 1);
    const ll  eb = (ll)x[tok] * cD, pb = (ll)s * cD;
    float4 o;
    o.x = inp(E, eb + t * 4 + 0, md) + inp(P, pb + t * 4 + 0, md);
    o.y = inp(E, eb + t * 4 + 1, md) + inp(P, pb + t * 4 + 1, md);
    o.z = inp(E, eb + t * 4 + 2, md) + inp(P, pb + t * 4 + 2, md);
    o.w = inp(E, eb + t * 4 + 3, md) + inp(P, pb + t * 4 + 3, md);
    ((float4*)(res + (size_t)tok * cD))[t] = o;
}

// ---------------- layernorm (unbiased std, ddof=1), f32 in, bf16 out ------------------
__global__ __launch_bounds__(192)
void ln_k(const float* __restrict__ in, const void* __restrict__ w,
          const void* __restrict__ b, ll wb_off, u16* __restrict__ out,
          const int* __restrict__ modeflag)
{
    __shared__ float sm[8];
    const int md = *modeflag;
    const int row = blockIdx.x, t = threadIdx.x;
    const float4 x = ((const float4*)(in + (size_t)row * cD))[t];
    float s = wave_sum(x.x + x.y + x.z + x.w);
    const int lane = t & 63, wv = t >> 6;
    if (!lane) sm[wv] = s;
    __syncthreads();
    const float mu = (sm[0] + sm[1] + sm[2]) * (1.f / (float)cD);
    const float dx = x.x - mu, dy = x.y - mu, dz = x.z - mu, dw = x.w - mu;
    float ss = wave_sum(dx * dx + dy * dy + dz * dz + dw * dw);
    if (!lane) sm[4 + wv] = ss;
    __syncthreads();
    const float var = (sm[4] + sm[5] + sm[6]) * (1.f / (float)(cD - 1));
    const float rs  = 1.f / sqrtf(var);
    const ll o4 = wb_off + (ll)t * 4;
    ushort4 o;
    o.x = f2b(inp(w, o4 + 0, md) * (dx * rs) + inp(b, o4 + 0, md));
    o.y = f2b(inp(w, o4 + 1, md) * (dy * rs) + inp(b, o4 + 1, md));
    o.z = f2b(inp(w, o4 + 2, md) * (dz * rs) + inp(b, o4 + 2, md));
    o.w = f2b(inp(w, o4 + 3, md) * (dw * rs) + inp(b, o4 + 3, md));
    ((ushort4*)(out + (size_t)row * cD))[t] = o;
}

// ---------------- causal softmax, in-place on bf16 [rows=BH*S][S] ----------------------
__global__ __launch_bounds__(256)
void softmax_k(u16* __restrict__ p)
{
    __shared__ float sm[8];
    const int row = blockIdx.x;
    const int q = row & (cS - 1);
    u16* pr = p + (size_t)row * cS;
    const int t = threadIdx.x;
    const int j0 = t * 4;
    ushort4 v = {0, 0, 0, 0};
    if (j0 <= q) v = ((const ushort4*)pr)[t];
    float x0 = (j0 + 0 <= q) ? b2f(v.x) : -100000.f;
    float x1 = (j0 + 1 <= q) ? b2f(v.y) : -100000.f;
    float x2 = (j0 + 2 <= q) ? b2f(v.z) : -100000.f;
    float x3 = (j0 + 3 <= q) ? b2f(v.w) : -100000.f;
    float mx = wave_max(fmaxf(fmaxf(x0, x1), fmaxf(x2, x3)));
    const int lane = t & 63, wv = t >> 6;
    if (!lane) sm[wv] = mx;
    __syncthreads();
    const float MX = fmaxf(fmaxf(sm[0], sm[1]), fmaxf(sm[2], sm[3]));
    const float e0 = expf(x0 - MX), e1 = expf(x1 - MX), e2 = expf(x2 - MX), e3 = expf(x3 - MX);
    float ssum = wave_sum(e0 + e1 + e2 + e3);
    if (!lane) sm[4 + wv] = ssum;
    __syncthreads();
    const float inv = 1.f / (sm[4] + sm[5] + sm[6] + sm[7]);
    ushort4 o;
    o.x = f2b(e0 * inv); o.y = f2b(e1 * inv); o.z = f2b(e2 * inv); o.w = f2b(e3 * inv);
    ((ushort4*)pr)[t] = o;
}

// =====================================================================================
extern "C" void kernel_launch(void* const* d_in, const int* in_sizes, int n_in,
                              void* d_out, int out_size, void* d_ws, size_t ws_size,
                              hipStream_t stream)
{
    (void)in_sizes; (void)n_in; (void)out_size;
    const int*  x     = (const int*)d_in[0];
    const void* E_w   = d_in[1];
    const void* P_w   = d_in[2];
    const void* ln1_w = d_in[3];
    const void* ln1_b = d_in[4];
    const void* Q_w   = d_in[5];
    const void* Q_b   = d_in[6];
    const void* K_w   = d_in[7];
    const void* K_b   = d_in[8];
    const void* V_w   = d_in[9];
    const void* V_b   = d_in[10];
    const void* O_w   = d_in[11];
    const void* O_b   = d_in[12];
    const void* ln2_w = d_in[13];
    const void* ln2_b = d_in[14];
    const void* In_w  = d_in[15];
    const void* In_b  = d_in[16];
    const void* Out_w = d_in[17];
    const void* Out_b = d_in[18];
    const void* lnf_w = d_in[19];
    const void* lnf_b = d_in[20];
    const void* U_w   = d_in[21];
    const void* U_b   = d_in[22];

    // ---- workspace carve with aliasing (~99 MB) ----
    char* wp = (char*)d_ws;
    auto carve = [&](size_t bytes) { char* r = wp; wp += (bytes + 255) & ~(size_t)255; return r; };
    int*   modeflag = (int*)carve(256);
    float* biasQKV  = (float*)carve((size_t)cL * cQKV * 4);
    float* res   = (float*)carve((size_t)cT * cD * 4);
    float* resat = (float*)carve((size_t)cT * cD * 4);
    u16* h     = (u16*)carve((size_t)cT * cD * 2);
    u16* attnb = (u16*)carve((size_t)cT * cD * 2);
    u16* vt    = (u16*)carve((size_t)cT * cD * 2);
    u16* qkv   = (u16*)carve((size_t)cT * cM * 2);       // aliased by mlpb
    u16* mlpb  = qkv;
    u16* WqkvT = (u16*)carve((size_t)cQKV * cD * 2);
    u16* WoT   = (u16*)carve((size_t)cD * cD * 2);
    u16* WinT  = (u16*)carve((size_t)cD * cM * 2);
    u16* WoutT = (u16*)carve((size_t)cD * cM * 2);
    u16* pbuf  = (u16*)carve((size_t)cBH * cS * cS * 2);
    u16* WuT   = pbuf;                                   // alias (pbuf dead after layers)

    if (ws_size && (size_t)(wp - (char*)d_ws) > ws_size) return;  // tripwire

    detect_k<<<1, 64, 0, stream>>>((const uint*)E_w, modeflag);
    packbias_k<<<(cL * cQKV) / 256, 256, 0, stream>>>(Q_b, K_b, V_b, biasQKV, modeflag);
    embed_k<<<cT, 192, 0, stream>>>(x, E_w, P_w, res, modeflag);

    for (int l = 0; l < cL; ++l) {
        // fused weight transposes for this layer (1 launch)
        transw_k<<<6912, 256, 0, stream>>>(Q_w, K_w, V_w, O_w, In_w, Out_w,
                                           WqkvT, WoT, WinT, WoutT, l, modeflag);

        // LN1
        ln_k<<<cT, 192, 0, stream>>>(res, ln1_w, ln1_b, (ll)l * cD, h, modeflag);

        // fused QKV projection (gemm_bt 128^2, 288 blocks): [2048,768] @ [2304,768]^T
        gemm_bt<128, 128, 2, 2, 1, false, true, false, false, 2>
            <<<dim3(cT / 128, cQKV / 128, 1), 256, 0, stream>>>(
            h, cD, 0, 0, WqkvT, cD, 0, 0, qkv, cQKV, 0, 0, 1, cD,
            biasQKV, (ll)l * cQKV, 1.f, nullptr, nullptr, modeflag);

        // V slice -> vt [B,H,DH,S]
        transpose_b_k<<<dim3(2, cS / 32, cBH), 256, 0, stream>>>(
            qkv + 2 * cD, vt, cS, cDH, cQKV, cS,
            (ll)cS * cQKV, cDH, (ll)cH * cDH * cS, (ll)cDH * cS, cH);

        // logits = Q K^T * 1/8, batched over (b,h), compact triangular grid (36 tiles)
        gemm_bt<128, 128, 2, 2, 1, false, false, true, false, 0>
            <<<dim3(36, 1, cBH), 256, 0, stream>>>(
            qkv, cQKV, (ll)cS * cQKV, cDH,
            qkv + cD, cQKV, (ll)cS * cQKV, cDH,
            pbuf, cS, (ll)cH * cS * cS, (ll)cS * cS,
            cH, cDH, nullptr, 0, 0.125f, nullptr, nullptr, modeflag);

        softmax_k<<<cBH * cS, 256, 0, stream>>>(pbuf);

        // attn = P V, batched, causal K-limit; 64x64 tiles -> 384 blocks
        gemm_bt<64, 64, 2, 2, 1, false, false, false, true, 0>
            <<<dim3(1, 16, cBH), 256, 0, stream>>>(
            pbuf, cS, (ll)cH * cS * cS, (ll)cS * cS,
            vt, cS, (ll)cH * cDH * cS, (ll)cDH * cS,
            attnb, cD, (ll)cS * cD, cDH,
            cH, cS, nullptr, 0, 1.f, nullptr, nullptr, modeflag);

        // O projection + residual -> resat (f32)
        gemm_bt<128, 128, 2, 2, 0, false, true, false, false, 1>
            <<<dim3(cT / 128, cD / 128, 1), 256, 0, stream>>>(
            attnb, cD, 0, 0, WoT, cD, 0, 0, resat, cD, 0, 0, 1, cD,
            O_b, (ll)l * cD, 1.f, res, nullptr, modeflag);

        // LN2
        ln_k<<<cT, 192, 0, stream>>>(resat, ln2_w, ln2_b, (ll)l * cD, h, modeflag);

        // MLP in (gemm_bt 128^2, 384 blocks): gelu(h @ Win + bIn)
        gemm_bt<128, 128, 2, 2, 1, true, true, false, false, 1>
            <<<dim3(cT / 128, cM / 128, 1), 256, 0, stream>>>(
            h, cD, 0, 0, WinT, cD, 0, 0, mlpb, cM, 0, 0, 1, cD,
            In_b, (ll)l * cM, 1.f, nullptr, nullptr, modeflag);

        // MLP out + double residual (64^2 tiles -> 384 blocks)
        gemm_bt<64, 64, 2, 2, 0, false, true, false, false, 1>
            <<<dim3(cT / 64, cD / 64, 1), 256, 0, stream>>>(
            mlpb, cM, 0, 0, WoutT, cM, 0, 0, res, cD, 0, 0, 1, cM,
            Out_b, (ll)l * cD, 1.f, res, resat, modeflag);
    }

    // unembed weight transpose (WuT aliases pbuf), final LN, unembed (gemm256 + T1 + NT)
    transpose_k<<<dim3(cV / 32, cD / 32, 1), 256, 0, stream>>>(
        U_w, WuT, cD, cV, cV, cD, 0, 0, 0, modeflag);
    ln_k<<<cT, 192, 0, stream>>>(res, lnf_w, lnf_b, 0, h, modeflag);
    gemm256<2, false, 1><<<dim3(cT / 256, cV / 256, 1), 512, 0, stream>>>(
        h, cD, WuT, cD, d_out, cV, cD, U_b, 0, modeflag);
}